// Round 4
// baseline (304.028 us; speedup 1.0000x reference)
//
#include <hip/hip_runtime.h>
#include <math.h>

#define N_NODES 50000
#define NP 50048          // padded to multiple of 64 for GEMM tiles
#define F_IN 128
#define HD 256            // HEADS*D_HEAD
#define HID 256
#define NE 800000
#define CAP 64
#define NEG_SLOPE 0.2f
#define NS (N_NODES * 64)         // per-head alpha stride
#define DST_SLICE 6250            // 50000 / 8

typedef __attribute__((ext_vector_type(8))) __bf16 bf16x8;
typedef __attribute__((ext_vector_type(4))) __bf16 bf16x4;
typedef __attribute__((ext_vector_type(4))) float f32x4;
typedef __attribute__((ext_vector_type(8))) unsigned short u16x8;

#define GLD_LDS16(g, l)                                                      \
    __builtin_amdgcn_global_load_lds(                                        \
        (const __attribute__((address_space(1))) unsigned int*)(g),          \
        (__attribute__((address_space(3))) unsigned int*)(l), 16, 0, 0)

// ---------------------------------------------------------------------------
// prep: x->bf16 convert, cnt/bucket init, 3 weight transposes. One launch.
#define PB_CONV 6250
#define PB_INIT 196
#define PB_WG   128
#define PB_W1   256
#define PB_W2   256

__global__ __launch_bounds__(256) void prep_kernel(const float* __restrict__ x,
                                                   const float* __restrict__ Wg,
                                                   const float* __restrict__ W1,
                                                   const float* __restrict__ W2,
                                                   __bf16* __restrict__ xb,
                                                   __bf16* __restrict__ Wg_t,
                                                   __bf16* __restrict__ W1_t,
                                                   __bf16* __restrict__ W2_t,
                                                   int* __restrict__ cnt,
                                                   unsigned short* __restrict__ bucket) {
    int b = blockIdx.x, t = threadIdx.x;
    if (b < PB_CONV) {                       // exactly N*F_IN/4 = 1.6M float4
        int i = b * 256 + t;
        float4 v = ((const float4*)x)[i];
        bf16x4 o = {(__bf16)v.x, (__bf16)v.y, (__bf16)v.z, (__bf16)v.w};
        ((bf16x4*)xb)[i] = o;
    } else if (b < PB_CONV + PB_INIT) {
        int n = (b - PB_CONV) * 256 + t;
        if (n < N_NODES) { cnt[n] = 1; bucket[n * CAP] = (unsigned short)n; }
    } else if (b < PB_CONV + PB_INIT + PB_WG) {
        int i = (b - PB_CONV - PB_INIT) * 256 + t;   // 32768 = HD*F_IN
        int m = i >> 7, k = i & 127;
        Wg_t[i] = (__bf16)Wg[(size_t)k * HD + m];
    } else if (b < PB_CONV + PB_INIT + PB_WG + PB_W1) {
        int i = (b - PB_CONV - PB_INIT - PB_WG) * 256 + t;  // 65536
        int m = i >> 8, k = i & 255;
        W1_t[i] = (__bf16)W1[(size_t)k * HID + m];
    } else {
        int i = (b - PB_CONV - PB_INIT - PB_WG - PB_W1) * 256 + t;
        int m = i >> 8, k = i & 255;
        W2_t[i] = (__bf16)W2[(size_t)k * HID + m];
    }
}

// ---------------------------------------------------------------------------
// fill v3: XCD-sliced by dst range so each XCD's cnt/bucket slice is
// L2-resident (no write-allocate thrash). slice = blockIdx & 7 (round-robin
// XCD dispatch heuristic). Edge dst array re-read 8x (sequential, L3-served).
// int64-vs-int32 detection via per-wave ballot of high words.
__global__ __launch_bounds__(256) void fill_kernel(const int* __restrict__ ew,
                                                   int* cnt,
                                                   unsigned short* __restrict__ bucket) {
    int b = blockIdx.x;
    int xcd = b & 7, chunk = b >> 3;
    int e = chunk * 256 + threadIdx.x;   // chunks cover exactly NE
    int hi = ew[2 * e + 1];
    unsigned long long bal = __ballot(hi != 0);
    int src, dst;
    if (bal == 0) { src = ew[2 * e]; dst = ew[2 * NE + 2 * e]; }  // int64
    else          { src = ew[e];     dst = ew[NE + e]; }          // int32
    int lo = xcd * DST_SLICE;
    if (dst >= lo && dst < lo + DST_SLICE) {
        int pos = atomicAdd(&cnt[dst], 1);
        if (pos < CAP) bucket[dst * CAP + pos] = (unsigned short)src;
    }
}

// ---------------------------------------------------------------------------
// GEMM1 (x @ W_gat) fused with attention coefficients.
// Tile 64 rows x 256 cols, 4 waves (each 64x64, col_off = wv*64 = head*64).
__global__ __launch_bounds__(256) void gemm1_attn_kernel(const __bf16* __restrict__ A,
                                                         const __bf16* __restrict__ Bt,
                                                         const float* __restrict__ att_src,
                                                         const float* __restrict__ att_dst,
                                                         __bf16* __restrict__ h,
                                                         float* __restrict__ a_s,
                                                         float* __restrict__ a_d) {
    __shared__ __bf16 As[64 * 32];    // [row][k]
    __shared__ __bf16 Bs[256 * 32];   // [col][k]
    const int t = threadIdx.x;
    const int lane = t & 63, wv = t >> 6;
    const int lr = lane & 15, q = lane >> 4, lk = q * 8;
    const int col_off = wv * 64;
    const int row0 = blockIdx.x * 64;
    const int sr = t >> 2, sk = (t & 3) * 8;

    f32x4 acc[4][4];
#pragma unroll
    for (int r = 0; r < 4; ++r)
#pragma unroll
        for (int c = 0; c < 4; ++c) acc[r][c] = f32x4{0.f, 0.f, 0.f, 0.f};

    for (int k0 = 0; k0 < F_IN; k0 += 32) {
        GLD_LDS16(&A[(size_t)(row0 + sr) * F_IN + k0 + sk], &As[sr * 32 + sk]);
#pragma unroll
        for (int s = 0; s < 4; ++s) {
            int r = s * 64 + sr;
            GLD_LDS16(&Bt[(size_t)r * F_IN + k0 + sk], &Bs[r * 32 + sk]);
        }
        __syncthreads();
        bf16x8 af[4], bfr[4];
#pragma unroll
        for (int i = 0; i < 4; ++i) {
            af[i]  = *(const bf16x8*)&As[(i * 16 + lr) * 32 + lk];
            bfr[i] = *(const bf16x8*)&Bs[(col_off + i * 16 + lr) * 32 + lk];
        }
#pragma unroll
        for (int r = 0; r < 4; ++r)
#pragma unroll
            for (int c = 0; c < 4; ++c)
                acc[r][c] = __builtin_amdgcn_mfma_f32_16x16x32_bf16(af[r], bfr[c], acc[r][c], 0, 0, 0);
        __syncthreads();
    }

    float asv[4], adv[4];
#pragma unroll
    for (int c = 0; c < 4; ++c) {
        int col = col_off + c * 16 + lr;
        asv[c] = att_src[col];
        adv[c] = att_dst[col];
    }
    float ps[4][4], pd[4][4];
#pragma unroll
    for (int r = 0; r < 4; ++r)
#pragma unroll
        for (int i = 0; i < 4; ++i) { ps[r][i] = 0.f; pd[r][i] = 0.f; }

#pragma unroll
    for (int c = 0; c < 4; ++c) {
        int col = col_off + c * 16 + lr;
#pragma unroll
        for (int r = 0; r < 4; ++r) {
#pragma unroll
            for (int i = 0; i < 4; ++i) {
                int row = row0 + r * 16 + q * 4 + i;   // < NP by construction
                float v = acc[r][c][i];
                h[(size_t)row * HD + col] = (__bf16)v;
                ps[r][i] += v * asv[c];
                pd[r][i] += v * adv[c];
            }
        }
    }
#pragma unroll
    for (int r = 0; r < 4; ++r)
#pragma unroll
        for (int i = 0; i < 4; ++i) {
#pragma unroll
            for (int m = 1; m < 16; m <<= 1) {
                ps[r][i] += __shfl_xor(ps[r][i], m);
                pd[r][i] += __shfl_xor(pd[r][i], m);
            }
        }
    if (lr == 0) {
#pragma unroll
        for (int r = 0; r < 4; ++r)
#pragma unroll
            for (int i = 0; i < 4; ++i) {
                int row = row0 + r * 16 + q * 4 + i;
                a_s[row * 4 + wv] = ps[r][i];
                a_d[row * 4 + wv] = pd[r][i];
            }
    }
}

__device__ __forceinline__ float lrelu(float v) { return v >= 0.f ? v : NEG_SLOPE * v; }

// ---------------------------------------------------------------------------
// Per-destination softmax -> alpha fp16 [head][node][slot]. One wave/node.
__global__ __launch_bounds__(256) void attn_softmax_kernel(const float* __restrict__ a_s,
                                                           const float* __restrict__ a_d,
                                                           const int* __restrict__ cnt,
                                                           const unsigned short* __restrict__ bucket,
                                                           _Float16* __restrict__ alpha_out) {
    int lane = threadIdx.x & 63;
    int wv = threadIdx.x >> 6;
    int n = blockIdx.x * 4 + wv;   // grid exactly 12500*4

    int deg = cnt[n];
    if (deg > CAP) deg = CAP;
    float4 e = {-1e30f, -1e30f, -1e30f, -1e30f};
    float4 ad = *(const float4*)&a_d[n * 4];
    if (lane < deg) {
        int src = bucket[n * CAP + lane];
        float4 as4 = *(const float4*)&a_s[src * 4];
        e.x = lrelu(as4.x + ad.x);
        e.y = lrelu(as4.y + ad.y);
        e.z = lrelu(as4.z + ad.z);
        e.w = lrelu(as4.w + ad.w);
    }
    float4 m = e;
#pragma unroll
    for (int off = 1; off < 64; off <<= 1) {
        m.x = fmaxf(m.x, __shfl_xor(m.x, off));
        m.y = fmaxf(m.y, __shfl_xor(m.y, off));
        m.z = fmaxf(m.z, __shfl_xor(m.z, off));
        m.w = fmaxf(m.w, __shfl_xor(m.w, off));
    }
    float4 wgt = {0, 0, 0, 0};
    if (lane < deg) {
        wgt.x = __expf(e.x - m.x); wgt.y = __expf(e.y - m.y);
        wgt.z = __expf(e.z - m.z); wgt.w = __expf(e.w - m.w);
    }
    float4 s = wgt;
#pragma unroll
    for (int off = 1; off < 64; off <<= 1) {
        s.x += __shfl_xor(s.x, off); s.y += __shfl_xor(s.y, off);
        s.z += __shfl_xor(s.z, off); s.w += __shfl_xor(s.w, off);
    }
    int base = n * 64 + lane;
    alpha_out[0 * NS + base] = (_Float16)(wgt.x / s.x);
    alpha_out[1 * NS + base] = (_Float16)(wgt.y / s.y);
    alpha_out[2 * NS + base] = (_Float16)(wgt.z / s.z);
    alpha_out[3 * NS + base] = (_Float16)(wgt.w / s.w);
}

// ---------------------------------------------------------------------------
// Column-partitioned gather: slice = blockIdx&7 owns 32 cols, so each XCD's
// h working set is 3.2 MB (L2-resident). Block: 32 nodes x 1 slice.
// Wave: 8 nodes x 8 lanes (bf16x4 = 4 cols each).
__global__ __launch_bounds__(256) void gather_kernel(const __bf16* __restrict__ h,
                                                     const _Float16* __restrict__ alpha,
                                                     const int* __restrict__ cnt,
                                                     const unsigned short* __restrict__ bucket,
                                                     const float* __restrict__ b_gat,
                                                     __bf16* __restrict__ gat) {
    __shared__ unsigned short s_src[32 * 64];
    __shared__ _Float16 s_al[32 * 64];
    __shared__ int s_deg[32];
    const int b = blockIdx.x;
    const int slice = b & 7;            // XCD swizzle
    const int n0 = (b >> 3) * 32;
    const int head = slice >> 1;
    const int t = threadIdx.x;

    {   // cooperative staging: 32 nodes x 64 slots of src (u16) + alpha (f16)
        int node = t >> 3;              // 0..31
        int off = (t & 7) * 8;          // 8 elements (16B)
        if (n0 + node < N_NODES) {
            *(u16x8*)&s_src[node * 64 + off] =
                *(const u16x8*)&bucket[(size_t)(n0 + node) * 64 + off];
            *(u16x8*)&s_al[node * 64 + off] =
                *(const u16x8*)&alpha[(size_t)head * NS + (size_t)(n0 + node) * 64 + off];
        }
        if (t < 32) {
            int n = n0 + t;
            int d = (n < N_NODES) ? cnt[n] : 0;
            s_deg[t] = d > CAP ? CAP : d;
        }
    }
    __syncthreads();

    const int lane = t & 63, wv = t >> 6;
    const int g = lane >> 3;            // node sub-index 0..7
    const int node = wv * 8 + g;        // 0..31
    const int cidx = (lane & 7) * 4;    // col within slice
    const int n = n0 + node;
    const int deg = s_deg[node];
    int md = deg;                        // wave-max of deg (groups differ)
#pragma unroll
    for (int off = 8; off < 64; off <<= 1) md = max(md, __shfl_xor(md, off));

    const __bf16* hsl = h + slice * 32 + cidx;
    float ax = 0.f, ay = 0.f, az = 0.f, aw = 0.f;
    for (int j = 0; j < md; ++j) {
        int sj = s_src[node * 64 + j];          // LDS broadcast within group
        float aj = (float)s_al[node * 64 + j];
        if (j < deg) {
            bf16x4 hv = *(const bf16x4*)&hsl[sj << 8];
            ax += aj * (float)hv.x; ay += aj * (float)hv.y;
            az += aj * (float)hv.z; aw += aj * (float)hv.w;
        }
    }
    if (n < N_NODES) {
        float4 bg = *(const float4*)&b_gat[slice * 32 + cidx];
        bf16x4 o = {(__bf16)(ax + bg.x), (__bf16)(ay + bg.y),
                    (__bf16)(az + bg.z), (__bf16)(aw + bg.w)};
        *(bf16x4*)&gat[(size_t)n * HD + slice * 32 + cidx] = o;
    }
}

// ---------------------------------------------------------------------------
// Fused MLP: out = relu(relu(gat@W1+b1)@W2+b2)@W3 + b3, one kernel.
__global__ __launch_bounds__(256) void fused_mlp_kernel(const __bf16* __restrict__ A,
                                                        const __bf16* __restrict__ W1t,
                                                        const __bf16* __restrict__ W2t,
                                                        const float* __restrict__ b1,
                                                        const float* __restrict__ b2,
                                                        const float* __restrict__ W3,
                                                        const float* __restrict__ b3,
                                                        float* __restrict__ out) {
    __shared__ __bf16 As[64 * 32];        // 4 KB
    __shared__ __bf16 Ws[256 * 32];       // 16 KB
    __shared__ __bf16 h1s[8 * 64 * 32];   // 32 KB, chunk c holds k in [32c,32c+32)
    __shared__ float s_out[64][2];
    const int t = threadIdx.x;
    const int lane = t & 63, wv = t >> 6;
    const int lr = lane & 15, q = lane >> 4, lk = q * 8;
    const int col_off = wv * 64;
    const int row0 = blockIdx.x * 64;
    const int sr = t >> 2, sk = (t & 3) * 8;

    if (t < 128) ((float*)s_out)[t] = 0.f;

    f32x4 acc[4][4];
#pragma unroll
    for (int r = 0; r < 4; ++r)
#pragma unroll
        for (int c = 0; c < 4; ++c) acc[r][c] = f32x4{0.f, 0.f, 0.f, 0.f};

    // ---- stage 1: h1 = relu(gat @ W1 + b1) -> LDS
    for (int k0 = 0; k0 < HD; k0 += 32) {
        GLD_LDS16(&A[(size_t)(row0 + sr) * HD + k0 + sk], &As[sr * 32 + sk]);
#pragma unroll
        for (int s = 0; s < 4; ++s) {
            int r = s * 64 + sr;
            GLD_LDS16(&W1t[(size_t)r * HD + k0 + sk], &Ws[r * 32 + sk]);
        }
        __syncthreads();
        bf16x8 af[4], bfr[4];
#pragma unroll
        for (int i = 0; i < 4; ++i) {
            af[i]  = *(const bf16x8*)&As[(i * 16 + lr) * 32 + lk];
            bfr[i] = *(const bf16x8*)&Ws[(col_off + i * 16 + lr) * 32 + lk];
        }
#pragma unroll
        for (int r = 0; r < 4; ++r)
#pragma unroll
            for (int c = 0; c < 4; ++c)
                acc[r][c] = __builtin_amdgcn_mfma_f32_16x16x32_bf16(af[r], bfr[c], acc[r][c], 0, 0, 0);
        __syncthreads();
    }
#pragma unroll
    for (int c = 0; c < 4; ++c) {
        int col = col_off + c * 16 + lr;
        float bv = b1[col];
        int cb = (col >> 5) * 2048;
        int kk = col & 31;
#pragma unroll
        for (int r = 0; r < 4; ++r)
#pragma unroll
            for (int i = 0; i < 4; ++i) {
                int row = r * 16 + q * 4 + i;
                float v = fmaxf(acc[r][c][i] + bv, 0.f);
                h1s[cb + row * 32 + kk] = (__bf16)v;
                acc[r][c][i] = 0.f;
            }
    }
    __syncthreads();

    // ---- stage 2: h2 = h1 @ W2
    for (int k0 = 0; k0 < HID; k0 += 32) {
#pragma unroll
        for (int s = 0; s < 4; ++s) {
            int r = s * 64 + sr;
            GLD_LDS16(&W2t[(size_t)r * HID + k0 + sk], &Ws[r * 32 + sk]);
        }
        __syncthreads();
        const int cb = (k0 >> 5) * 2048;
        bf16x8 af[4], bfr[4];
#pragma unroll
        for (int i = 0; i < 4; ++i) {
            af[i]  = *(const bf16x8*)&h1s[cb + (i * 16 + lr) * 32 + lk];
            bfr[i] = *(const bf16x8*)&Ws[(col_off + i * 16 + lr) * 32 + lk];
        }
#pragma unroll
        for (int r = 0; r < 4; ++r)
#pragma unroll
            for (int c = 0; c < 4; ++c)
                acc[r][c] = __builtin_amdgcn_mfma_f32_16x16x32_bf16(af[r], bfr[c], acc[r][c], 0, 0, 0);
        __syncthreads();
    }

    // ---- stage 3: out = relu(h2+b2) @ W3 + b3 (fp32 throughout)
    float b2v[4], w30[4], w31[4];
#pragma unroll
    for (int c = 0; c < 4; ++c) {
        int col = col_off + c * 16 + lr;
        b2v[c] = b2[col];
        w30[c] = W3[col * 2];
        w31[c] = W3[col * 2 + 1];
    }
#pragma unroll
    for (int r = 0; r < 4; ++r) {
#pragma unroll
        for (int i = 0; i < 4; ++i) {
            float o0 = 0.f, o1 = 0.f;
#pragma unroll
            for (int c = 0; c < 4; ++c) {
                float v = fmaxf(acc[r][c][i] + b2v[c], 0.f);
                o0 += v * w30[c];
                o1 += v * w31[c];
            }
#pragma unroll
            for (int m = 1; m < 16; m <<= 1) {
                o0 += __shfl_xor(o0, m);
                o1 += __shfl_xor(o1, m);
            }
            if (lr == 0) {
                int row = r * 16 + q * 4 + i;
                atomicAdd(&s_out[row][0], o0);
                atomicAdd(&s_out[row][1], o1);
            }
        }
    }
    __syncthreads();
    if (t < 128) {
        int row = t >> 1, o = t & 1;
        int g = row0 + row;
        if (g < N_NODES) out[g * 2 + o] = s_out[row][o] + b3[o];
    }
}

// ---------------------------------------------------------------------------
extern "C" void kernel_launch(void* const* d_in, const int* in_sizes, int n_in,
                              void* d_out, int out_size, void* d_ws, size_t ws_size,
                              hipStream_t stream) {
    const float* x       = (const float*)d_in[0];
    const int*   ei      = (const int*)d_in[1];
    const float* W_gat   = (const float*)d_in[2];
    const float* att_src = (const float*)d_in[3];
    const float* att_dst = (const float*)d_in[4];
    const float* b_gat   = (const float*)d_in[5];
    const float* W1      = (const float*)d_in[6];
    const float* b1      = (const float*)d_in[7];
    const float* W2      = (const float*)d_in[8];
    const float* b2      = (const float*)d_in[9];
    const float* W3      = (const float*)d_in[10];
    const float* b3      = (const float*)d_in[11];
    float* out = (float*)d_out;

    char* ws = (char*)d_ws;
    __bf16* x_bf   = (__bf16*)ws;  ws += (size_t)NP * F_IN * 2;
    __bf16* h_bf   = (__bf16*)ws;  ws += (size_t)NP * HD * 2;
    __bf16* gat_bf = (__bf16*)ws;  ws += (size_t)NP * HD * 2;
    __bf16* Wg_t   = (__bf16*)ws;  ws += (size_t)HD * F_IN * 2;
    __bf16* W1_t   = (__bf16*)ws;  ws += (size_t)HID * HD * 2;
    __bf16* W2_t   = (__bf16*)ws;  ws += (size_t)HID * HID * 2;
    float* a_s     = (float*)ws;   ws += (size_t)NP * 4 * 4;
    float* a_d     = (float*)ws;   ws += (size_t)NP * 4 * 4;
    _Float16* alp  = (_Float16*)ws; ws += (size_t)4 * NS * 2;       // 25.6 MB
    int* cnt       = (int*)ws;     ws += (size_t)N_NODES * 4;
    unsigned short* bucket = (unsigned short*)ws;
    ws += (size_t)N_NODES * CAP * 2;

    prep_kernel<<<PB_CONV + PB_INIT + PB_WG + PB_W1 + PB_W2, 256, 0, stream>>>(
        x, W_gat, W1, W2, x_bf, Wg_t, W1_t, W2_t, cnt, bucket);
    fill_kernel<<<(NE / 256) * 8, 256, 0, stream>>>(ei, cnt, bucket);
    gemm1_attn_kernel<<<NP / 64, 256, 0, stream>>>(x_bf, Wg_t, att_src, att_dst,
                                                   h_bf, a_s, a_d);
    attn_softmax_kernel<<<N_NODES / 4, 256, 0, stream>>>(a_s, a_d, cnt, bucket, alp);
    gather_kernel<<<((N_NODES + 31) / 32) * 8, 256, 0, stream>>>(h_bf, alp, cnt, bucket,
                                                                 b_gat, gat_bf);
    fused_mlp_kernel<<<NP / 64, 256, 0, stream>>>(gat_bf, W1_t, W2_t, b1, b2, W3, b3, out);
}

// Round 5
// 253.523 us; speedup vs baseline: 1.1992x; 1.1992x over previous
//
#include <hip/hip_runtime.h>
#include <math.h>

#define N_NODES 50000
#define NP 50048          // padded to multiple of 64 for GEMM tiles
#define F_IN 128
#define HD 256            // HEADS*D_HEAD
#define HID 256
#define NE 800000
#define CAP 64
#define NEG_SLOPE 0.2f

typedef __attribute__((ext_vector_type(8))) __bf16 bf16x8;
typedef __attribute__((ext_vector_type(4))) __bf16 bf16x4;
typedef __attribute__((ext_vector_type(4))) float f32x4;

#define GLD_LDS16(g, l)                                                      \
    __builtin_amdgcn_global_load_lds(                                        \
        (const __attribute__((address_space(1))) unsigned int*)(g),          \
        (__attribute__((address_space(3))) unsigned int*)(l), 16, 0, 0)

// ---------------------------------------------------------------------------
// prep: cnt/bucket init + 3 weight transposes. One launch.
#define PB_INIT 196
#define PB_WG   128
#define PB_W1   256
#define PB_W2   256

__global__ __launch_bounds__(256) void prep_kernel(const float* __restrict__ Wg,
                                                   const float* __restrict__ W1,
                                                   const float* __restrict__ W2,
                                                   __bf16* __restrict__ Wg_t,
                                                   __bf16* __restrict__ W1_t,
                                                   __bf16* __restrict__ W2_t,
                                                   int* __restrict__ cnt,
                                                   unsigned short* __restrict__ bucket) {
    int b = blockIdx.x, t = threadIdx.x;
    if (b < PB_INIT) {
        int n = b * 256 + t;
        if (n < N_NODES) { cnt[n] = 1; bucket[n * CAP] = (unsigned short)n; }
    } else if (b < PB_INIT + PB_WG) {
        int i = (b - PB_INIT) * 256 + t;             // 32768 = HD*F_IN
        int m = i >> 7, k = i & 127;
        Wg_t[i] = (__bf16)Wg[(size_t)k * HD + m];
    } else if (b < PB_INIT + PB_WG + PB_W1) {
        int i = (b - PB_INIT - PB_WG) * 256 + t;     // 65536
        int m = i >> 8, k = i & 255;
        W1_t[i] = (__bf16)W1[(size_t)k * HID + m];
    } else {
        int i = (b - PB_INIT - PB_WG - PB_W1) * 256 + t;
        int m = i >> 8, k = i & 255;
        W2_t[i] = (__bf16)W2[(size_t)k * HID + m];
    }
}

// ---------------------------------------------------------------------------
// fill: single pass; int64-vs-int32 detection via per-wave ballot of high
// words (int64 => all high words zero). u16 bucket (node ids < 65536).
__global__ __launch_bounds__(256) void fill_kernel(const int* __restrict__ ew,
                                                   int* cnt,
                                                   unsigned short* __restrict__ bucket) {
    int e = blockIdx.x * 256 + threadIdx.x;   // grid is exactly NE/256
    int hi = ew[2 * e + 1];
    unsigned long long bal = __ballot(hi != 0);
    int src, dst;
    if (bal == 0) { src = ew[2 * e]; dst = ew[2 * NE + 2 * e]; }  // int64
    else          { src = ew[e];     dst = ew[NE + e]; }          // int32
    int pos = atomicAdd(&cnt[dst], 1);
    if (pos < CAP) bucket[dst * CAP + pos] = (unsigned short)src;
}

// ---------------------------------------------------------------------------
// GEMM1 (x @ W_gat) fused with: fp32->bf16 convert of x (in A-staging) and
// attention coefficients (in epilogue).
// Tile 64 rows x 256 cols, 4 waves (each 64x64, col_off = wv*64 = head*64).
__global__ __launch_bounds__(256) void gemm1_attn_kernel(const float* __restrict__ x,
                                                         const __bf16* __restrict__ Bt,
                                                         const float* __restrict__ att_src,
                                                         const float* __restrict__ att_dst,
                                                         __bf16* __restrict__ h,
                                                         float* __restrict__ a_s,
                                                         float* __restrict__ a_d) {
    __shared__ __bf16 As[64 * 32];    // [row][k]
    __shared__ __bf16 Bs[256 * 32];   // [col][k]
    const int t = threadIdx.x;
    const int lane = t & 63, wv = t >> 6;
    const int lr = lane & 15, q = lane >> 4, lk = q * 8;
    const int col_off = wv * 64;
    const int row0 = blockIdx.x * 64;
    const int sr = t >> 2, sk = (t & 3) * 8;
    const int arow = row0 + sr;
    const bool avalid = arow < N_NODES;

    f32x4 acc[4][4];
#pragma unroll
    for (int r = 0; r < 4; ++r)
#pragma unroll
        for (int c = 0; c < 4; ++c) acc[r][c] = f32x4{0.f, 0.f, 0.f, 0.f};

    for (int k0 = 0; k0 < F_IN; k0 += 32) {
        // A staging: load x fp32, convert to bf16, ds_write (fused convert)
        float4 v0 = {0, 0, 0, 0}, v1 = {0, 0, 0, 0};
        if (avalid) {
            const float* xp = &x[(size_t)arow * F_IN + k0 + sk];
            v0 = *(const float4*)xp;
            v1 = *(const float4*)(xp + 4);
        }
        bf16x8 o;
        o[0] = (__bf16)v0.x; o[1] = (__bf16)v0.y; o[2] = (__bf16)v0.z; o[3] = (__bf16)v0.w;
        o[4] = (__bf16)v1.x; o[5] = (__bf16)v1.y; o[6] = (__bf16)v1.z; o[7] = (__bf16)v1.w;
        *(bf16x8*)&As[sr * 32 + sk] = o;
        // B staging: async global->LDS
#pragma unroll
        for (int s = 0; s < 4; ++s) {
            int r = s * 64 + sr;
            GLD_LDS16(&Bt[(size_t)r * F_IN + k0 + sk], &Bs[r * 32 + sk]);
        }
        __syncthreads();
        bf16x8 af[4], bfr[4];
#pragma unroll
        for (int i = 0; i < 4; ++i) {
            af[i]  = *(const bf16x8*)&As[(i * 16 + lr) * 32 + lk];
            bfr[i] = *(const bf16x8*)&Bs[(col_off + i * 16 + lr) * 32 + lk];
        }
#pragma unroll
        for (int r = 0; r < 4; ++r)
#pragma unroll
            for (int c = 0; c < 4; ++c)
                acc[r][c] = __builtin_amdgcn_mfma_f32_16x16x32_bf16(af[r], bfr[c], acc[r][c], 0, 0, 0);
        __syncthreads();
    }

    float asv[4], adv[4];
#pragma unroll
    for (int c = 0; c < 4; ++c) {
        int col = col_off + c * 16 + lr;
        asv[c] = att_src[col];
        adv[c] = att_dst[col];
    }
    float ps[4][4], pd[4][4];
#pragma unroll
    for (int r = 0; r < 4; ++r)
#pragma unroll
        for (int i = 0; i < 4; ++i) { ps[r][i] = 0.f; pd[r][i] = 0.f; }

#pragma unroll
    for (int c = 0; c < 4; ++c) {
        int col = col_off + c * 16 + lr;
#pragma unroll
        for (int r = 0; r < 4; ++r) {
#pragma unroll
            for (int i = 0; i < 4; ++i) {
                int row = row0 + r * 16 + q * 4 + i;   // < NP by construction
                float v = acc[r][c][i];
                h[(size_t)row * HD + col] = (__bf16)v;
                ps[r][i] += v * asv[c];
                pd[r][i] += v * adv[c];
            }
        }
    }
#pragma unroll
    for (int r = 0; r < 4; ++r)
#pragma unroll
        for (int i = 0; i < 4; ++i) {
#pragma unroll
            for (int m = 1; m < 16; m <<= 1) {
                ps[r][i] += __shfl_xor(ps[r][i], m);
                pd[r][i] += __shfl_xor(pd[r][i], m);
            }
        }
    if (lr == 0) {
#pragma unroll
        for (int r = 0; r < 4; ++r)
#pragma unroll
            for (int i = 0; i < 4; ++i) {
                int row = row0 + r * 16 + q * 4 + i;
                a_s[row * 4 + wv] = ps[r][i];
                a_d[row * 4 + wv] = pd[r][i];
            }
    }
}

__device__ __forceinline__ float lrelu(float v) { return v >= 0.f ? v : NEG_SLOPE * v; }

// ---------------------------------------------------------------------------
// Fused per-destination softmax + weighted gather-aggregate. One wave/node.
// Gather phase: dwordx4 loads covering TWO source rows per wave instruction
// (lanes 0-31 -> source j, lanes 32-63 -> source j+1), 2-pair unroll.
__global__ __launch_bounds__(256) void gat_aggregate_kernel(const __bf16* __restrict__ h,
                                                            const float* __restrict__ a_s,
                                                            const float* __restrict__ a_d,
                                                            const int* __restrict__ cnt,
                                                            const unsigned short* __restrict__ bucket,
                                                            const float* __restrict__ b_gat,
                                                            __bf16* __restrict__ gat) {
    __shared__ unsigned short s_src[4][64];
    __shared__ float s_alpha[4][64][4];
    int lane = threadIdx.x & 63;
    int wv = threadIdx.x >> 6;
    int n = blockIdx.x * 4 + wv;   // grid is exactly 12500*4 = 50000

    int deg = cnt[n];
    if (deg > CAP) deg = CAP;
    int src = n;                   // self for invalid lanes (alpha=0)
    float4 e = {-1e30f, -1e30f, -1e30f, -1e30f};
    float4 ad = *(const float4*)&a_d[n * 4];
    if (lane < deg) {
        src = bucket[n * CAP + lane];
        float4 as4 = *(const float4*)&a_s[src * 4];
        e.x = lrelu(as4.x + ad.x);
        e.y = lrelu(as4.y + ad.y);
        e.z = lrelu(as4.z + ad.z);
        e.w = lrelu(as4.w + ad.w);
    }
    float4 m = e;
#pragma unroll
    for (int off = 1; off < 64; off <<= 1) {
        m.x = fmaxf(m.x, __shfl_xor(m.x, off));
        m.y = fmaxf(m.y, __shfl_xor(m.y, off));
        m.z = fmaxf(m.z, __shfl_xor(m.z, off));
        m.w = fmaxf(m.w, __shfl_xor(m.w, off));
    }
    float4 wgt = {0, 0, 0, 0};
    if (lane < deg) {
        wgt.x = __expf(e.x - m.x); wgt.y = __expf(e.y - m.y);
        wgt.z = __expf(e.z - m.z); wgt.w = __expf(e.w - m.w);
    }
    float4 s = wgt;
#pragma unroll
    for (int off = 1; off < 64; off <<= 1) {
        s.x += __shfl_xor(s.x, off); s.y += __shfl_xor(s.y, off);
        s.z += __shfl_xor(s.z, off); s.w += __shfl_xor(s.w, off);
    }
    s_src[wv][lane] = (unsigned short)src;
    s_alpha[wv][lane][0] = wgt.x / s.x;
    s_alpha[wv][lane][1] = wgt.y / s.y;
    s_alpha[wv][lane][2] = wgt.z / s.z;
    s_alpha[wv][lane][3] = wgt.w / s.w;
    __syncthreads();

    // gather: lane handles 8 cols at c0; half selects even/odd source of pair
    const int half = lane >> 5;
    const int l32 = lane & 31;
    const int c0 = l32 * 8;
    const int head = l32 >> 3;
    float acc[8];
#pragma unroll
    for (int k = 0; k < 8; ++k) acc[k] = 0.f;

    const int mde = (deg + 1) & ~1;
    int j = 0;
    for (; j + 4 <= mde; j += 4) {
        int j0 = j + half, j1 = j + 2 + half;
        int s0 = s_src[wv][j0], s1 = s_src[wv][j1];
        float a0 = s_alpha[wv][j0][head], a1 = s_alpha[wv][j1][head];
        bf16x8 h0 = *(const bf16x8*)&h[(size_t)s0 * HD + c0];
        bf16x8 h1 = *(const bf16x8*)&h[(size_t)s1 * HD + c0];
#pragma unroll
        for (int k = 0; k < 8; ++k)
            acc[k] += a0 * (float)h0[k] + a1 * (float)h1[k];
    }
    for (; j < mde; j += 2) {
        int j0 = j + half;
        int s0 = s_src[wv][j0];
        float a0 = s_alpha[wv][j0][head];
        bf16x8 h0 = *(const bf16x8*)&h[(size_t)s0 * HD + c0];
#pragma unroll
        for (int k = 0; k < 8; ++k)
            acc[k] += a0 * (float)h0[k];
    }
    // combine the two halves
#pragma unroll
    for (int k = 0; k < 8; ++k) acc[k] += __shfl_xor(acc[k], 32);

    if (half == 0) {
        float4 bg0 = *(const float4*)&b_gat[c0];
        float4 bg1 = *(const float4*)&b_gat[c0 + 4];
        bf16x8 o;
        o[0] = (__bf16)(acc[0] + bg0.x); o[1] = (__bf16)(acc[1] + bg0.y);
        o[2] = (__bf16)(acc[2] + bg0.z); o[3] = (__bf16)(acc[3] + bg0.w);
        o[4] = (__bf16)(acc[4] + bg1.x); o[5] = (__bf16)(acc[5] + bg1.y);
        o[6] = (__bf16)(acc[6] + bg1.z); o[7] = (__bf16)(acc[7] + bg1.w);
        *(bf16x8*)&gat[(size_t)n * HD + c0] = o;
    }
}

// ---------------------------------------------------------------------------
// Fused MLP: out = relu(relu(gat@W1+b1)@W2+b2)@W3 + b3, one kernel.
__global__ __launch_bounds__(256) void fused_mlp_kernel(const __bf16* __restrict__ A,
                                                        const __bf16* __restrict__ W1t,
                                                        const __bf16* __restrict__ W2t,
                                                        const float* __restrict__ b1,
                                                        const float* __restrict__ b2,
                                                        const float* __restrict__ W3,
                                                        const float* __restrict__ b3,
                                                        float* __restrict__ out) {
    __shared__ __bf16 As[64 * 32];        // 4 KB
    __shared__ __bf16 Ws[256 * 32];       // 16 KB
    __shared__ __bf16 h1s[8 * 64 * 32];   // 32 KB, chunk c holds k in [32c,32c+32)
    __shared__ float s_out[64][2];
    const int t = threadIdx.x;
    const int lane = t & 63, wv = t >> 6;
    const int lr = lane & 15, q = lane >> 4, lk = q * 8;
    const int col_off = wv * 64;
    const int row0 = blockIdx.x * 64;
    const int sr = t >> 2, sk = (t & 3) * 8;

    if (t < 128) ((float*)s_out)[t] = 0.f;

    f32x4 acc[4][4];
#pragma unroll
    for (int r = 0; r < 4; ++r)
#pragma unroll
        for (int c = 0; c < 4; ++c) acc[r][c] = f32x4{0.f, 0.f, 0.f, 0.f};

    // ---- stage 1: h1 = relu(gat @ W1 + b1) -> LDS
    for (int k0 = 0; k0 < HD; k0 += 32) {
        GLD_LDS16(&A[(size_t)(row0 + sr) * HD + k0 + sk], &As[sr * 32 + sk]);
#pragma unroll
        for (int s = 0; s < 4; ++s) {
            int r = s * 64 + sr;
            GLD_LDS16(&W1t[(size_t)r * HD + k0 + sk], &Ws[r * 32 + sk]);
        }
        __syncthreads();
        bf16x8 af[4], bfr[4];
#pragma unroll
        for (int i = 0; i < 4; ++i) {
            af[i]  = *(const bf16x8*)&As[(i * 16 + lr) * 32 + lk];
            bfr[i] = *(const bf16x8*)&Ws[(col_off + i * 16 + lr) * 32 + lk];
        }
#pragma unroll
        for (int r = 0; r < 4; ++r)
#pragma unroll
            for (int c = 0; c < 4; ++c)
                acc[r][c] = __builtin_amdgcn_mfma_f32_16x16x32_bf16(af[r], bfr[c], acc[r][c], 0, 0, 0);
        __syncthreads();
    }
#pragma unroll
    for (int c = 0; c < 4; ++c) {
        int col = col_off + c * 16 + lr;
        float bv = b1[col];
        int cb = (col >> 5) * 2048;
        int kk = col & 31;
#pragma unroll
        for (int r = 0; r < 4; ++r)
#pragma unroll
            for (int i = 0; i < 4; ++i) {
                int row = r * 16 + q * 4 + i;
                float v = fmaxf(acc[r][c][i] + bv, 0.f);
                h1s[cb + row * 32 + kk] = (__bf16)v;
                acc[r][c][i] = 0.f;
            }
    }
    __syncthreads();

    // ---- stage 2: h2 = h1 @ W2
    for (int k0 = 0; k0 < HID; k0 += 32) {
#pragma unroll
        for (int s = 0; s < 4; ++s) {
            int r = s * 64 + sr;
            GLD_LDS16(&W2t[(size_t)r * HID + k0 + sk], &Ws[r * 32 + sk]);
        }
        __syncthreads();
        const int cb = (k0 >> 5) * 2048;
        bf16x8 af[4], bfr[4];
#pragma unroll
        for (int i = 0; i < 4; ++i) {
            af[i]  = *(const bf16x8*)&h1s[cb + (i * 16 + lr) * 32 + lk];
            bfr[i] = *(const bf16x8*)&Ws[(col_off + i * 16 + lr) * 32 + lk];
        }
#pragma unroll
        for (int r = 0; r < 4; ++r)
#pragma unroll
            for (int c = 0; c < 4; ++c)
                acc[r][c] = __builtin_amdgcn_mfma_f32_16x16x32_bf16(af[r], bfr[c], acc[r][c], 0, 0, 0);
        __syncthreads();
    }

    // ---- stage 3: out = relu(h2+b2) @ W3 + b3 (fp32 throughout)
    float b2v[4], w30[4], w31[4];
#pragma unroll
    for (int c = 0; c < 4; ++c) {
        int col = col_off + c * 16 + lr;
        b2v[c] = b2[col];
        w30[c] = W3[col * 2];
        w31[c] = W3[col * 2 + 1];
    }
#pragma unroll
    for (int r = 0; r < 4; ++r) {
#pragma unroll
        for (int i = 0; i < 4; ++i) {
            float o0 = 0.f, o1 = 0.f;
#pragma unroll
            for (int c = 0; c < 4; ++c) {
                float v = fmaxf(acc[r][c][i] + b2v[c], 0.f);
                o0 += v * w30[c];
                o1 += v * w31[c];
            }
#pragma unroll
            for (int m = 1; m < 16; m <<= 1) {
                o0 += __shfl_xor(o0, m);
                o1 += __shfl_xor(o1, m);
            }
            if (lr == 0) {
                int row = r * 16 + q * 4 + i;
                atomicAdd(&s_out[row][0], o0);
                atomicAdd(&s_out[row][1], o1);
            }
        }
    }
    __syncthreads();
    if (t < 128) {
        int row = t >> 1, o = t & 1;
        int g = row0 + row;
        if (g < N_NODES) out[g * 2 + o] = s_out[row][o] + b3[o];
    }
}

// ---------------------------------------------------------------------------
extern "C" void kernel_launch(void* const* d_in, const int* in_sizes, int n_in,
                              void* d_out, int out_size, void* d_ws, size_t ws_size,
                              hipStream_t stream) {
    const float* x       = (const float*)d_in[0];
    const int*   ei      = (const int*)d_in[1];
    const float* W_gat   = (const float*)d_in[2];
    const float* att_src = (const float*)d_in[3];
    const float* att_dst = (const float*)d_in[4];
    const float* b_gat   = (const float*)d_in[5];
    const float* W1      = (const float*)d_in[6];
    const float* b1      = (const float*)d_in[7];
    const float* W2      = (const float*)d_in[8];
    const float* b2      = (const float*)d_in[9];
    const float* W3      = (const float*)d_in[10];
    const float* b3      = (const float*)d_in[11];
    float* out = (float*)d_out;

    char* ws = (char*)d_ws;
    __bf16* h_bf   = (__bf16*)ws;  ws += (size_t)NP * HD * 2;
    __bf16* gat_bf = (__bf16*)ws;  ws += (size_t)NP * HD * 2;
    __bf16* Wg_t   = (__bf16*)ws;  ws += (size_t)HD * F_IN * 2;
    __bf16* W1_t   = (__bf16*)ws;  ws += (size_t)HID * HD * 2;
    __bf16* W2_t   = (__bf16*)ws;  ws += (size_t)HID * HID * 2;
    float* a_s     = (float*)ws;   ws += (size_t)NP * 4 * 4;
    float* a_d     = (float*)ws;   ws += (size_t)NP * 4 * 4;
    int* cnt       = (int*)ws;     ws += (size_t)N_NODES * 4;
    unsigned short* bucket = (unsigned short*)ws;
    ws += (size_t)N_NODES * CAP * 2;

    prep_kernel<<<PB_INIT + PB_WG + PB_W1 + PB_W2, 256, 0, stream>>>(
        W_gat, W1, W2, Wg_t, W1_t, W2_t, cnt, bucket);
    fill_kernel<<<NE / 256, 256, 0, stream>>>(ei, cnt, bucket);
    gemm1_attn_kernel<<<NP / 64, 256, 0, stream>>>(x, Wg_t, att_src, att_dst,
                                                   h_bf, a_s, a_d);
    gat_aggregate_kernel<<<N_NODES / 4, 256, 0, stream>>>(h_bf, a_s, a_d, cnt, bucket,
                                                          b_gat, gat_bf);
    fused_mlp_kernel<<<NP / 64, 256, 0, stream>>>(gat_bf, W1_t, W2_t, b1, b2, W3, b3, out);
}

// Round 6
// 240.660 us; speedup vs baseline: 1.2633x; 1.0535x over previous
//
#include <hip/hip_runtime.h>
#include <math.h>

#define N_NODES 50000
#define NP 50048          // padded to multiple of 64 for GEMM tiles
#define F_IN 128
#define HD 256            // HEADS*D_HEAD
#define HID 256
#define NE 800000
#define CAP 64
#define NEG_SLOPE 0.2f
#define G1_BLOCKS (NP / 64)       // 782 gemm1 blocks in the combined launch

typedef __attribute__((ext_vector_type(8))) __bf16 bf16x8;
typedef __attribute__((ext_vector_type(4))) __bf16 bf16x4;
typedef __attribute__((ext_vector_type(4))) float f32x4;

#define GLD_LDS16(g, l)                                                      \
    __builtin_amdgcn_global_load_lds(                                        \
        (const __attribute__((address_space(1))) unsigned int*)(g),          \
        (__attribute__((address_space(3))) unsigned int*)(l), 16, 0, 0)

// ---------------------------------------------------------------------------
// prep: cnt/bucket init + 3 weight transposes. One launch.
#define PB_INIT 196
#define PB_WG   128
#define PB_W1   256
#define PB_W2   256

__global__ __launch_bounds__(256) void prep_kernel(const float* __restrict__ Wg,
                                                   const float* __restrict__ W1,
                                                   const float* __restrict__ W2,
                                                   __bf16* __restrict__ Wg_t,
                                                   __bf16* __restrict__ W1_t,
                                                   __bf16* __restrict__ W2_t,
                                                   int* __restrict__ cnt,
                                                   unsigned short* __restrict__ bucket) {
    int b = blockIdx.x, t = threadIdx.x;
    if (b < PB_INIT) {
        int n = b * 256 + t;
        if (n < N_NODES) { cnt[n] = 1; bucket[n * CAP] = (unsigned short)n; }
    } else if (b < PB_INIT + PB_WG) {
        int i = (b - PB_INIT) * 256 + t;             // 32768 = HD*F_IN
        int m = i >> 7, k = i & 127;
        Wg_t[i] = (__bf16)Wg[(size_t)k * HD + m];
    } else if (b < PB_INIT + PB_WG + PB_W1) {
        int i = (b - PB_INIT - PB_WG) * 256 + t;     // 65536
        int m = i >> 8, k = i & 255;
        W1_t[i] = (__bf16)W1[(size_t)k * HID + m];
    } else {
        int i = (b - PB_INIT - PB_WG - PB_W1) * 256 + t;
        int m = i >> 8, k = i & 255;
        W2_t[i] = (__bf16)W2[(size_t)k * HID + m];
    }
}

// ---------------------------------------------------------------------------
// Combined launch: blocks [0, G1_BLOCKS) run GEMM1 (x @ W_gat, fused fp32->
// bf16 convert + attention coefficients); blocks [G1_BLOCKS, +NE/256) run the
// edge-bucket fill. The two are independent; merging them overlaps fill's
// atomic/latency phase with GEMM1's MFMA phase and saves a dispatch gap.
__global__ __launch_bounds__(256) void g1_fill_kernel(const float* __restrict__ x,
                                                      const __bf16* __restrict__ Bt,
                                                      const float* __restrict__ att_src,
                                                      const float* __restrict__ att_dst,
                                                      const int* __restrict__ ew,
                                                      __bf16* __restrict__ h,
                                                      float* __restrict__ a_s,
                                                      float* __restrict__ a_d,
                                                      int* __restrict__ cnt,
                                                      unsigned short* __restrict__ bucket) {
    __shared__ __bf16 As[64 * 32];    // [row][k]
    __shared__ __bf16 Bs[256 * 32];   // [col][k]

    if (blockIdx.x >= G1_BLOCKS) {
        // ---- fill branch: int64-vs-int32 detection via per-wave ballot of
        // high words (int64 => all high words zero). u16 bucket (ids < 65536).
        int e = (blockIdx.x - G1_BLOCKS) * 256 + threadIdx.x;  // covers NE
        int hi = ew[2 * e + 1];
        unsigned long long bal = __ballot(hi != 0);
        int src, dst;
        if (bal == 0) { src = ew[2 * e]; dst = ew[2 * NE + 2 * e]; }  // int64
        else          { src = ew[e];     dst = ew[NE + e]; }          // int32
        int pos = atomicAdd(&cnt[dst], 1);
        if (pos < CAP) bucket[dst * CAP + pos] = (unsigned short)src;
        return;
    }

    // ---- GEMM1 branch: tile 64 rows x 256 cols, 4 waves (col_off = head*64)
    const int t = threadIdx.x;
    const int lane = t & 63, wv = t >> 6;
    const int lr = lane & 15, q = lane >> 4, lk = q * 8;
    const int col_off = wv * 64;
    const int row0 = blockIdx.x * 64;
    const int sr = t >> 2, sk = (t & 3) * 8;
    const int arow = row0 + sr;
    const bool avalid = arow < N_NODES;

    f32x4 acc[4][4];
#pragma unroll
    for (int r = 0; r < 4; ++r)
#pragma unroll
        for (int c = 0; c < 4; ++c) acc[r][c] = f32x4{0.f, 0.f, 0.f, 0.f};

    for (int k0 = 0; k0 < F_IN; k0 += 32) {
        // A staging: load x fp32, convert to bf16, ds_write (fused convert)
        float4 v0 = {0, 0, 0, 0}, v1 = {0, 0, 0, 0};
        if (avalid) {
            const float* xp = &x[(size_t)arow * F_IN + k0 + sk];
            v0 = *(const float4*)xp;
            v1 = *(const float4*)(xp + 4);
        }
        bf16x8 o;
        o[0] = (__bf16)v0.x; o[1] = (__bf16)v0.y; o[2] = (__bf16)v0.z; o[3] = (__bf16)v0.w;
        o[4] = (__bf16)v1.x; o[5] = (__bf16)v1.y; o[6] = (__bf16)v1.z; o[7] = (__bf16)v1.w;
        *(bf16x8*)&As[sr * 32 + sk] = o;
        // B staging: async global->LDS
#pragma unroll
        for (int s = 0; s < 4; ++s) {
            int r = s * 64 + sr;
            GLD_LDS16(&Bt[(size_t)r * F_IN + k0 + sk], &Bs[r * 32 + sk]);
        }
        __syncthreads();
        bf16x8 af[4], bfr[4];
#pragma unroll
        for (int i = 0; i < 4; ++i) {
            af[i]  = *(const bf16x8*)&As[(i * 16 + lr) * 32 + lk];
            bfr[i] = *(const bf16x8*)&Bs[(col_off + i * 16 + lr) * 32 + lk];
        }
#pragma unroll
        for (int r = 0; r < 4; ++r)
#pragma unroll
            for (int c = 0; c < 4; ++c)
                acc[r][c] = __builtin_amdgcn_mfma_f32_16x16x32_bf16(af[r], bfr[c], acc[r][c], 0, 0, 0);
        __syncthreads();
    }

    float asv[4], adv[4];
#pragma unroll
    for (int c = 0; c < 4; ++c) {
        int col = col_off + c * 16 + lr;
        asv[c] = att_src[col];
        adv[c] = att_dst[col];
    }
    float ps[4][4], pd[4][4];
#pragma unroll
    for (int r = 0; r < 4; ++r)
#pragma unroll
        for (int i = 0; i < 4; ++i) { ps[r][i] = 0.f; pd[r][i] = 0.f; }

#pragma unroll
    for (int c = 0; c < 4; ++c) {
        int col = col_off + c * 16 + lr;
#pragma unroll
        for (int r = 0; r < 4; ++r) {
#pragma unroll
            for (int i = 0; i < 4; ++i) {
                int row = row0 + r * 16 + q * 4 + i;   // < NP by construction
                float v = acc[r][c][i];
                h[(size_t)row * HD + col] = (__bf16)v;
                ps[r][i] += v * asv[c];
                pd[r][i] += v * adv[c];
            }
        }
    }
#pragma unroll
    for (int r = 0; r < 4; ++r)
#pragma unroll
        for (int i = 0; i < 4; ++i) {
#pragma unroll
            for (int m = 1; m < 16; m <<= 1) {
                ps[r][i] += __shfl_xor(ps[r][i], m);
                pd[r][i] += __shfl_xor(pd[r][i], m);
            }
        }
    if (lr == 0) {
#pragma unroll
        for (int r = 0; r < 4; ++r)
#pragma unroll
            for (int i = 0; i < 4; ++i) {
                int row = row0 + r * 16 + q * 4 + i;
                a_s[row * 4 + wv] = ps[r][i];
                a_d[row * 4 + wv] = pd[r][i];
            }
    }
}

__device__ __forceinline__ float lrelu(float v) { return v >= 0.f ? v : NEG_SLOPE * v; }

// ---------------------------------------------------------------------------
// Fused per-destination softmax + weighted gather-aggregate.
// ONE WAVE PER BLOCK (64 threads): decouples per-node retirement (no
// inter-wave tail coupling), single-wave barrier is near-free.
// Gather: dwordx4 over TWO source rows per instruction (lane-halves), main
// loop keeps 8 sources (4 loads/half) in flight.
__global__ __launch_bounds__(64) void gat_aggregate_kernel(const __bf16* __restrict__ h,
                                                           const float* __restrict__ a_s,
                                                           const float* __restrict__ a_d,
                                                           const int* __restrict__ cnt,
                                                           const unsigned short* __restrict__ bucket,
                                                           const float* __restrict__ b_gat,
                                                           __bf16* __restrict__ gat) {
    __shared__ unsigned short s_src[64];
    __shared__ float s_alpha[64][4];
    const int lane = threadIdx.x;
    const int n = blockIdx.x;          // grid is exactly N_NODES

    int deg = cnt[n];
    if (deg > CAP) deg = CAP;
    int src = n;                       // self for invalid lanes (alpha=0)
    float4 e = {-1e30f, -1e30f, -1e30f, -1e30f};
    float4 ad = *(const float4*)&a_d[n * 4];
    if (lane < deg) {
        src = bucket[n * CAP + lane];
        float4 as4 = *(const float4*)&a_s[src * 4];
        e.x = lrelu(as4.x + ad.x);
        e.y = lrelu(as4.y + ad.y);
        e.z = lrelu(as4.z + ad.z);
        e.w = lrelu(as4.w + ad.w);
    }
    float4 m = e;
#pragma unroll
    for (int off = 1; off < 64; off <<= 1) {
        m.x = fmaxf(m.x, __shfl_xor(m.x, off));
        m.y = fmaxf(m.y, __shfl_xor(m.y, off));
        m.z = fmaxf(m.z, __shfl_xor(m.z, off));
        m.w = fmaxf(m.w, __shfl_xor(m.w, off));
    }
    float4 wgt = {0, 0, 0, 0};
    if (lane < deg) {
        wgt.x = __expf(e.x - m.x); wgt.y = __expf(e.y - m.y);
        wgt.z = __expf(e.z - m.z); wgt.w = __expf(e.w - m.w);
    }
    float4 s = wgt;
#pragma unroll
    for (int off = 1; off < 64; off <<= 1) {
        s.x += __shfl_xor(s.x, off); s.y += __shfl_xor(s.y, off);
        s.z += __shfl_xor(s.z, off); s.w += __shfl_xor(s.w, off);
    }
    s_src[lane] = (unsigned short)src;
    s_alpha[lane][0] = wgt.x / s.x;
    s_alpha[lane][1] = wgt.y / s.y;
    s_alpha[lane][2] = wgt.z / s.z;
    s_alpha[lane][3] = wgt.w / s.w;
    __syncthreads();                   // single-wave: waitcnt + cheap barrier

    // gather: lane-half selects even/odd source of a pair; lane covers 8 cols
    const int half = lane >> 5;
    const int l32 = lane & 31;
    const int c0 = l32 * 8;
    const int head = l32 >> 3;
    float acc[8];
#pragma unroll
    for (int k = 0; k < 8; ++k) acc[k] = 0.f;

    const int mde = (deg + 1) & ~1;
    int j = 0;
    for (; j + 8 <= mde; j += 8) {     // 8 sources in flight (4 loads/half)
        int j0 = j + half, j1 = j + 2 + half, j2 = j + 4 + half, j3 = j + 6 + half;
        int s0 = s_src[j0], s1 = s_src[j1], s2 = s_src[j2], s3 = s_src[j3];
        float a0 = s_alpha[j0][head], a1 = s_alpha[j1][head];
        float a2 = s_alpha[j2][head], a3 = s_alpha[j3][head];
        bf16x8 h0 = *(const bf16x8*)&h[(size_t)s0 * HD + c0];
        bf16x8 h1 = *(const bf16x8*)&h[(size_t)s1 * HD + c0];
        bf16x8 h2 = *(const bf16x8*)&h[(size_t)s2 * HD + c0];
        bf16x8 h3 = *(const bf16x8*)&h[(size_t)s3 * HD + c0];
#pragma unroll
        for (int k = 0; k < 8; ++k)
            acc[k] += a0 * (float)h0[k] + a1 * (float)h1[k]
                    + a2 * (float)h2[k] + a3 * (float)h3[k];
    }
    for (; j < mde; j += 2) {
        int j0 = j + half;
        int s0 = s_src[j0];
        float a0 = s_alpha[j0][head];
        bf16x8 h0 = *(const bf16x8*)&h[(size_t)s0 * HD + c0];
#pragma unroll
        for (int k = 0; k < 8; ++k)
            acc[k] += a0 * (float)h0[k];
    }
    // combine the two halves
#pragma unroll
    for (int k = 0; k < 8; ++k) acc[k] += __shfl_xor(acc[k], 32);

    if (half == 0) {
        float4 bg0 = *(const float4*)&b_gat[c0];
        float4 bg1 = *(const float4*)&b_gat[c0 + 4];
        bf16x8 o;
        o[0] = (__bf16)(acc[0] + bg0.x); o[1] = (__bf16)(acc[1] + bg0.y);
        o[2] = (__bf16)(acc[2] + bg0.z); o[3] = (__bf16)(acc[3] + bg0.w);
        o[4] = (__bf16)(acc[4] + bg1.x); o[5] = (__bf16)(acc[5] + bg1.y);
        o[6] = (__bf16)(acc[6] + bg1.z); o[7] = (__bf16)(acc[7] + bg1.w);
        *(bf16x8*)&gat[(size_t)n * HD + c0] = o;
    }
}

// ---------------------------------------------------------------------------
// Fused MLP: out = relu(relu(gat@W1+b1)@W2+b2)@W3 + b3, one kernel.
__global__ __launch_bounds__(256) void fused_mlp_kernel(const __bf16* __restrict__ A,
                                                        const __bf16* __restrict__ W1t,
                                                        const __bf16* __restrict__ W2t,
                                                        const float* __restrict__ b1,
                                                        const float* __restrict__ b2,
                                                        const float* __restrict__ W3,
                                                        const float* __restrict__ b3,
                                                        float* __restrict__ out) {
    __shared__ __bf16 As[64 * 32];        // 4 KB
    __shared__ __bf16 Ws[256 * 32];       // 16 KB
    __shared__ __bf16 h1s[8 * 64 * 32];   // 32 KB, chunk c holds k in [32c,32c+32)
    __shared__ float s_out[64][2];
    const int t = threadIdx.x;
    const int lane = t & 63, wv = t >> 6;
    const int lr = lane & 15, q = lane >> 4, lk = q * 8;
    const int col_off = wv * 64;
    const int row0 = blockIdx.x * 64;
    const int sr = t >> 2, sk = (t & 3) * 8;

    if (t < 128) ((float*)s_out)[t] = 0.f;

    f32x4 acc[4][4];
#pragma unroll
    for (int r = 0; r < 4; ++r)
#pragma unroll
        for (int c = 0; c < 4; ++c) acc[r][c] = f32x4{0.f, 0.f, 0.f, 0.f};

    // ---- stage 1: h1 = relu(gat @ W1 + b1) -> LDS
    for (int k0 = 0; k0 < HD; k0 += 32) {
        GLD_LDS16(&A[(size_t)(row0 + sr) * HD + k0 + sk], &As[sr * 32 + sk]);
#pragma unroll
        for (int s = 0; s < 4; ++s) {
            int r = s * 64 + sr;
            GLD_LDS16(&W1t[(size_t)r * HD + k0 + sk], &Ws[r * 32 + sk]);
        }
        __syncthreads();
        bf16x8 af[4], bfr[4];
#pragma unroll
        for (int i = 0; i < 4; ++i) {
            af[i]  = *(const bf16x8*)&As[(i * 16 + lr) * 32 + lk];
            bfr[i] = *(const bf16x8*)&Ws[(col_off + i * 16 + lr) * 32 + lk];
        }
#pragma unroll
        for (int r = 0; r < 4; ++r)
#pragma unroll
            for (int c = 0; c < 4; ++c)
                acc[r][c] = __builtin_amdgcn_mfma_f32_16x16x32_bf16(af[r], bfr[c], acc[r][c], 0, 0, 0);
        __syncthreads();
    }
#pragma unroll
    for (int c = 0; c < 4; ++c) {
        int col = col_off + c * 16 + lr;
        float bv = b1[col];
        int cb = (col >> 5) * 2048;
        int kk = col & 31;
#pragma unroll
        for (int r = 0; r < 4; ++r)
#pragma unroll
            for (int i = 0; i < 4; ++i) {
                int row = r * 16 + q * 4 + i;
                float v = fmaxf(acc[r][c][i] + bv, 0.f);
                h1s[cb + row * 32 + kk] = (__bf16)v;
                acc[r][c][i] = 0.f;
            }
    }
    __syncthreads();

    // ---- stage 2: h2 = h1 @ W2
    for (int k0 = 0; k0 < HID; k0 += 32) {
#pragma unroll
        for (int s = 0; s < 4; ++s) {
            int r = s * 64 + sr;
            GLD_LDS16(&W2t[(size_t)r * HID + k0 + sk], &Ws[r * 32 + sk]);
        }
        __syncthreads();
        const int cb = (k0 >> 5) * 2048;
        bf16x8 af[4], bfr[4];
#pragma unroll
        for (int i = 0; i < 4; ++i) {
            af[i]  = *(const bf16x8*)&h1s[cb + (i * 16 + lr) * 32 + lk];
            bfr[i] = *(const bf16x8*)&Ws[(col_off + i * 16 + lr) * 32 + lk];
        }
#pragma unroll
        for (int r = 0; r < 4; ++r)
#pragma unroll
            for (int c = 0; c < 4; ++c)
                acc[r][c] = __builtin_amdgcn_mfma_f32_16x16x32_bf16(af[r], bfr[c], acc[r][c], 0, 0, 0);
        __syncthreads();
    }

    // ---- stage 3: out = relu(h2+b2) @ W3 + b3 (fp32 throughout)
    float b2v[4], w30[4], w31[4];
#pragma unroll
    for (int c = 0; c < 4; ++c) {
        int col = col_off + c * 16 + lr;
        b2v[c] = b2[col];
        w30[c] = W3[col * 2];
        w31[c] = W3[col * 2 + 1];
    }
#pragma unroll
    for (int r = 0; r < 4; ++r) {
#pragma unroll
        for (int i = 0; i < 4; ++i) {
            float o0 = 0.f, o1 = 0.f;
#pragma unroll
            for (int c = 0; c < 4; ++c) {
                float v = fmaxf(acc[r][c][i] + b2v[c], 0.f);
                o0 += v * w30[c];
                o1 += v * w31[c];
            }
#pragma unroll
            for (int m = 1; m < 16; m <<= 1) {
                o0 += __shfl_xor(o0, m);
                o1 += __shfl_xor(o1, m);
            }
            if (lr == 0) {
                int row = r * 16 + q * 4 + i;
                atomicAdd(&s_out[row][0], o0);
                atomicAdd(&s_out[row][1], o1);
            }
        }
    }
    __syncthreads();
    if (t < 128) {
        int row = t >> 1, o = t & 1;
        int g = row0 + row;
        if (g < N_NODES) out[g * 2 + o] = s_out[row][o] + b3[o];
    }
}

// ---------------------------------------------------------------------------
extern "C" void kernel_launch(void* const* d_in, const int* in_sizes, int n_in,
                              void* d_out, int out_size, void* d_ws, size_t ws_size,
                              hipStream_t stream) {
    const float* x       = (const float*)d_in[0];
    const int*   ei      = (const int*)d_in[1];
    const float* W_gat   = (const float*)d_in[2];
    const float* att_src = (const float*)d_in[3];
    const float* att_dst = (const float*)d_in[4];
    const float* b_gat   = (const float*)d_in[5];
    const float* W1      = (const float*)d_in[6];
    const float* b1      = (const float*)d_in[7];
    const float* W2      = (const float*)d_in[8];
    const float* b2      = (const float*)d_in[9];
    const float* W3      = (const float*)d_in[10];
    const float* b3      = (const float*)d_in[11];
    float* out = (float*)d_out;

    char* ws = (char*)d_ws;
    __bf16* h_bf   = (__bf16*)ws;  ws += (size_t)NP * HD * 2;
    __bf16* gat_bf = (__bf16*)ws;  ws += (size_t)NP * HD * 2;
    __bf16* Wg_t   = (__bf16*)ws;  ws += (size_t)HD * F_IN * 2;
    __bf16* W1_t   = (__bf16*)ws;  ws += (size_t)HID * HD * 2;
    __bf16* W2_t   = (__bf16*)ws;  ws += (size_t)HID * HID * 2;
    float* a_s     = (float*)ws;   ws += (size_t)NP * 4 * 4;
    float* a_d     = (float*)ws;   ws += (size_t)NP * 4 * 4;
    int* cnt       = (int*)ws;     ws += (size_t)N_NODES * 4;
    unsigned short* bucket = (unsigned short*)ws;
    ws += (size_t)N_NODES * CAP * 2;

    prep_kernel<<<PB_INIT + PB_WG + PB_W1 + PB_W2, 256, 0, stream>>>(
        W_gat, W1, W2, Wg_t, W1_t, W2_t, cnt, bucket);
    g1_fill_kernel<<<G1_BLOCKS + NE / 256, 256, 0, stream>>>(
        x, Wg_t, att_src, att_dst, ei, h_bf, a_s, a_d, cnt, bucket);
    gat_aggregate_kernel<<<N_NODES, 64, 0, stream>>>(h_bf, a_s, a_d, cnt, bucket,
                                                     b_gat, gat_bf);
    fused_mlp_kernel<<<NP / 64, 256, 0, stream>>>(gat_bf, W1_t, W2_t, b1, b2, W3, b3, out);
}